// Round 5
// baseline (225.878 us; speedup 1.0000x reference)
//
#include <hip/hip_runtime.h>
#include <cstdint>

#define DIM_ 768
#define H_ 6
#define HD_ 128
#define NB_ 4
#define SEQ_ 2048
#define TOK_ (NB_*SEQ_)
#define OUT3_ (3*DIM_)
#define L2E 1.4426950408889634f

typedef __bf16 bf16;
typedef __bf16 bf16x4 __attribute__((ext_vector_type(4)));
typedef __bf16 bf16x8 __attribute__((ext_vector_type(8)));
typedef float f32x4 __attribute__((ext_vector_type(4)));
typedef float f32x16 __attribute__((ext_vector_type(16)));
typedef unsigned int u32;
typedef u32 u32x4 __attribute__((ext_vector_type(4)));

__device__ __forceinline__ void gload16(const void* g, void* lds) {
  __builtin_amdgcn_global_load_lds((const __attribute__((address_space(1))) void*)g,
                                   (__attribute__((address_space(3))) void*)lds,
                                   16, 0, 0);
}

// ---------------- fp32 -> bf16 convert ----------------
__global__ void convert_kernel(const float* __restrict__ in, bf16* __restrict__ out, int n) {
  int i = (blockIdx.x * 256 + threadIdx.x) * 4;
  if (i >= n) return;
  float4 v = *reinterpret_cast<const float4*>(in + i);
  bf16x4 o = { (bf16)v.x, (bf16)v.y, (bf16)v.z, (bf16)v.w };
  *reinterpret_cast<bf16x4*>(out + i) = o;
}

// ---------------- mask kernel ----------------
__global__ void mask_kernel(const float* __restrict__ latency,
                            const float* __restrict__ rw,
                            const float* __restrict__ rb,
                            const float* __restrict__ g1,
                            const float* __restrict__ g2,
                            float* __restrict__ mask6) {
  int i = threadIdx.x;
  if (i < 6) {
    int j = (i < 4) ? 0 : (i - 3);
    float logit = rw[j] * latency[0] + rb[j];
    float z = (logit + g1[j] - g2[j]) / 5.0f;
    float ys = 1.0f / (1.0f + expf(-z));
    float yh = ys > 0.5f ? 1.0f : 0.0f;
    mask6[i] = (yh - ys) + ys;
  }
}

// ---------------- QKV GEMM (bf16 MFMA): qkv = x @ qkv_w^T + b ----------------
// q (scaled by 1/sqrt(d)*log2e) -> [bh][n][d], k -> [bh][n][d], v -> [bh][d][n]
__global__ __launch_bounds__(256)
void qkv_gemm(const bf16* __restrict__ A, const bf16* __restrict__ W,
              const float* __restrict__ bias,
              bf16* __restrict__ q, bf16* __restrict__ k, bf16* __restrict__ vt) {
  __shared__ bf16 As[128 * 32];
  __shared__ bf16 Bs[128 * 32];
  const int tid = threadIdx.x;
  const int l = tid & 63, w = tid >> 6;
  const int lr = l & 15, lg = l >> 4;
  const int wm = w >> 1, wn = w & 1;
  const int tm = blockIdx.y * 128;
  const int on = blockIdx.x * 128;

  f32x4 acc[4][4];
#pragma unroll
  for (int i = 0; i < 4; ++i)
#pragma unroll
    for (int j = 0; j < 4; ++j) acc[i][j] = f32x4{0.f, 0.f, 0.f, 0.f};

  for (int k0 = 0; k0 < DIM_; k0 += 32) {
    __syncthreads();
#pragma unroll
    for (int u = 0; u < 2; ++u) {
      int row = w * 32 + u * 16 + (l >> 2);
      int cb = l & 3;
      gload16(A + (size_t)(tm + row) * DIM_ + k0 + cb * 8, As + (w * 32 + u * 16) * 32);
      gload16(W + (size_t)(on + row) * DIM_ + k0 + cb * 8, Bs + (w * 32 + u * 16) * 32);
    }
    __syncthreads();
    bf16x8 af[4], bfr[4];
#pragma unroll
    for (int i = 0; i < 4; ++i)
      af[i] = *reinterpret_cast<const bf16x8*>(As + (wm * 64 + i * 16 + lr) * 32 + lg * 8);
#pragma unroll
    for (int j = 0; j < 4; ++j)
      bfr[j] = *reinterpret_cast<const bf16x8*>(Bs + (wn * 64 + j * 16 + lr) * 32 + lg * 8);
#pragma unroll
    for (int i = 0; i < 4; ++i)
#pragma unroll
      for (int j = 0; j < 4; ++j)
        acc[i][j] = __builtin_amdgcn_mfma_f32_16x16x32_bf16(af[i], bfr[j], acc[i][j], 0, 0, 0);
  }

  if (on < 2 * DIM_) {
    const int s = on / DIM_;
    const float scale = 0.08838834764831845f * L2E;
#pragma unroll
    for (int i = 0; i < 4; ++i) {
      int t = tm + wm * 64 + i * 16 + lg * 4;
#pragma unroll
      for (int j = 0; j < 4; ++j) {
        int o = on + wn * 64 + j * 16 + lr;
        int rem = o - s * DIM_;
        int hh = rem >> 7, d = rem & 127;
        float bia = bias[o];
#pragma unroll
        for (int r = 0; r < 4; ++r) {
          int tt = t + r;
          int bb = tt >> 11, n = tt & 2047;
          float val = acc[i][j][r] + bia;
          if (s == 0)
            q[((size_t)(bb * H_ + hh) * SEQ_ + n) * HD_ + d] = (bf16)(val * scale);
          else
            k[((size_t)(bb * H_ + hh) * SEQ_ + n) * HD_ + d] = (bf16)val;
        }
      }
    }
  } else {
    // v: transpose 128x128 tile through LDS, write [bh][d][n] coalesced
    const int hh = (on - 2 * DIM_) >> 7;
    const int bb = tm >> 11, n0 = tm & 2047;
    bf16(*Ts)[136] = reinterpret_cast<bf16(*)[136]>(As);
    for (int wc = 0; wc < 2; ++wc) {
#pragma unroll
      for (int j = 0; j < 4; ++j) {
        __syncthreads();
        if (wn == wc) {
          float bia = bias[on + wc * 64 + j * 16 + lr];
#pragma unroll
          for (int i = 0; i < 4; ++i) {
            bf16x4 pk;
#pragma unroll
            for (int r = 0; r < 4; ++r) pk[r] = (bf16)(acc[i][j][r] + bia);
            *reinterpret_cast<bf16x4*>(&Ts[lr][wm * 64 + i * 16 + lg * 4]) = pk;
          }
        }
        __syncthreads();
        int row = tid >> 4;
        int c8 = (tid & 15) * 8;
        bf16x8 v8 = *reinterpret_cast<const bf16x8*>(&Ts[row][c8]);
        int d = wc * 64 + j * 16 + row;
        *reinterpret_cast<bf16x8*>(
            vt + ((size_t)(bb * H_ + hh) * HD_ + d) * SEQ_ + n0 + c8) = v8;
      }
    }
  }
}

// ---------------- proj GEMM (bf16 MFMA): out = ab @ proj_w^T + b (fp32 out) ----------------
__global__ __launch_bounds__(256)
void proj_gemm(const bf16* __restrict__ A, const bf16* __restrict__ W,
               const float* __restrict__ bias, float* __restrict__ out) {
  __shared__ bf16 As[128 * 32];
  __shared__ bf16 Bs[128 * 32];
  const int tid = threadIdx.x;
  const int l = tid & 63, w = tid >> 6;
  const int lr = l & 15, lg = l >> 4;
  const int wm = w >> 1, wn = w & 1;
  const int tm = blockIdx.y * 128;
  const int on = blockIdx.x * 128;

  f32x4 acc[4][4];
#pragma unroll
  for (int i = 0; i < 4; ++i)
#pragma unroll
    for (int j = 0; j < 4; ++j) acc[i][j] = f32x4{0.f, 0.f, 0.f, 0.f};

  for (int k0 = 0; k0 < DIM_; k0 += 32) {
    __syncthreads();
#pragma unroll
    for (int u = 0; u < 2; ++u) {
      int row = w * 32 + u * 16 + (l >> 2);
      int cb = l & 3;
      gload16(A + (size_t)(tm + row) * DIM_ + k0 + cb * 8, As + (w * 32 + u * 16) * 32);
      gload16(W + (size_t)(on + row) * DIM_ + k0 + cb * 8, Bs + (w * 32 + u * 16) * 32);
    }
    __syncthreads();
    bf16x8 af[4], bfr[4];
#pragma unroll
    for (int i = 0; i < 4; ++i)
      af[i] = *reinterpret_cast<const bf16x8*>(As + (wm * 64 + i * 16 + lr) * 32 + lg * 8);
#pragma unroll
    for (int j = 0; j < 4; ++j)
      bfr[j] = *reinterpret_cast<const bf16x8*>(Bs + (wn * 64 + j * 16 + lr) * 32 + lg * 8);
#pragma unroll
    for (int i = 0; i < 4; ++i)
#pragma unroll
      for (int j = 0; j < 4; ++j)
        acc[i][j] = __builtin_amdgcn_mfma_f32_16x16x32_bf16(af[i], bfr[j], acc[i][j], 0, 0, 0);
  }

#pragma unroll
  for (int i = 0; i < 4; ++i) {
#pragma unroll
    for (int j = 0; j < 4; ++j) {
      int o = on + wn * 64 + j * 16 + lr;
      float bia = bias[o];
#pragma unroll
      for (int r = 0; r < 4; ++r) {
        int t = tm + wm * 64 + i * 16 + lg * 4 + r;
        out[(size_t)t * DIM_ + o] = acc[i][j][r] + bia;
      }
    }
  }
}

// ---------------- flash attention, 32x32x16 MFMA, in-register softmax ----------------
// QBLK=64 (2 waves x 32 q-rows), KVBLK=64, grid = 24 bh x 32 qtiles = 768 blocks
__global__ __launch_bounds__(128)
void attn_kernel(const bf16* __restrict__ qb, const bf16* __restrict__ kb,
                 const bf16* __restrict__ vtb, const float* __restrict__ mask6,
                 bf16* __restrict__ ab) {
  __shared__ bf16 Ks[64 * 128];    // LDS[row][blk16] = K[row][blk16 ^ (row&7)]
  __shared__ bf16 Vts[128 * 64];   // LDS[d][blk16]   = Vt[d][blk16 ^ (d&7)]

  const int tid = threadIdx.x;
  const int l = tid & 63;
  const int wq = tid >> 6;         // 2 waves, 32 q-rows each
  const int kl = l & 31;
  const int hi = l >> 5;
  const int bid = blockIdx.x;
  const int bh = bid % 24;         // all q-tiles of a head on one XCD
  const int qt = bid / 24;
  const int h = bh % H_;
  const int b = bh / H_;
  const int q0 = qt * 64 + wq * 32;

  const bf16* qg = qb + (size_t)bh * SEQ_ * HD_;
  const bf16* kg = kb + (size_t)bh * SEQ_ * HD_;
  const bf16* vg = vtb + (size_t)bh * HD_ * SEQ_;

  // Q B-fragments in regs: lane (q=kl, hi) holds Q[q][kc*16 + hi*8 .. +7]
  bf16x8 qf[8];
#pragma unroll
  for (int kc = 0; kc < 8; ++kc)
    qf[kc] = *reinterpret_cast<const bf16x8*>(
        qg + (size_t)(q0 + kl) * HD_ + kc * 16 + hi * 8);

  f32x16 oacc[4];
#pragma unroll
  for (int df = 0; df < 4; ++df)
#pragma unroll
    for (int r = 0; r < 16; ++r) oacc[df][r] = 0.f;
  float m_lane = -3.0e38f;   // running max for q-row = kl (log2 units)
  float lsum = 0.f;          // per-half-wave partial row sum (merged in epilogue)

  for (int j0 = 0; j0 < SEQ_; j0 += 64) {
    __syncthreads();               // previous tile's LDS reads complete
    // stage K [64][128] and Vt [128][64], 16B-block XOR swizzle via global source
#pragma unroll
    for (int u = 0; u < 8; ++u) {
      int rbase = wq * 32 + u * 4;
      int row = rbase + (l >> 4);
      gload16(kg + (size_t)(j0 + row) * HD_ + (((l & 15) ^ (row & 7)) << 3),
              Ks + rbase * 128);
      int dbase = wq * 64 + u * 8;
      int d = dbase + (l >> 3);
      gload16(vg + (size_t)d * SEQ_ + j0 + (((l & 7) ^ (d & 7)) << 3),
              Vts + dbase * 64);
    }
    __syncthreads();               // compiler drains vmcnt(0) before barrier

    // S^T = K Q^T : lane (q=kl, hi) holds S[key][q], key = kf*32 + (r&3)+8*(r>>2)+4*hi
    f32x16 sacc[2];
#pragma unroll
    for (int kf = 0; kf < 2; ++kf)
#pragma unroll
      for (int r = 0; r < 16; ++r) sacc[kf][r] = 0.f;
    __builtin_amdgcn_s_setprio(1);
#pragma unroll
    for (int kc = 0; kc < 8; ++kc)
#pragma unroll
      for (int kf = 0; kf < 2; ++kf) {
        int row = kf * 32 + kl;
        int byteoff = row * 256 + ((((kc << 1) + hi) ^ (kl & 7)) << 4);
        bf16x8 kfr = *reinterpret_cast<const bf16x8*>((const char*)Ks + byteoff);
        sacc[kf] = __builtin_amdgcn_mfma_f32_32x32x16_bf16(kfr, qf[kc], sacc[kf], 0, 0, 0);
      }
    __builtin_amdgcn_s_setprio(0);

    // lane-local online softmax for q-row = kl
    float t = sacc[0][0];
#pragma unroll
    for (int kf = 0; kf < 2; ++kf)
#pragma unroll
      for (int r = 0; r < 16; ++r) t = fmaxf(t, sacc[kf][r]);
    t = fmaxf(t, __shfl_xor(t, 32));
    bool need = t > m_lane + 8.0f;  // defer-max (P bounded by 2^8)
    if (__ballot(need) != 0ull) {
      float nm = fmaxf(m_lane, t);
      float c = exp2f(m_lane - nm);
      m_lane = nm;
      lsum *= c;
#pragma unroll
      for (int r = 0; r < 16; ++r) {
        float cr = __shfl(c, (r & 3) + 8 * (r >> 2) + 4 * hi);
#pragma unroll
        for (int df = 0; df < 4; ++df) oacc[df][r] *= cr;
      }
    }

    // P = exp2(S - m) -> bf16 pairs pp[frag][8]
    u32 pp[2][8];
#pragma unroll
    for (int kf = 0; kf < 2; ++kf)
#pragma unroll
      for (int m = 0; m < 8; ++m) {
        float e0 = exp2f(sacc[kf][2 * m] - m_lane);
        float e1 = exp2f(sacc[kf][2 * m + 1] - m_lane);
        lsum += e0 + e1;
        union { u32 u; bf16 hh2[2]; } pk;
        pk.hh2[0] = (bf16)e0; pk.hh2[1] = (bf16)e1;
        pp[kf][m] = pk.u;
      }

    // A-fragments for PV via permlane32_swap (8 swaps):
    // af[ks] word p: pair m = 4*(ks&1) + 2*hi_t + (p&1), source half = p>>1
    u32x4 afv[4];
#pragma unroll
    for (int ks = 0; ks < 4; ++ks) {
      int f = ks >> 1, k2 = ks & 1;
#pragma unroll
      for (int i = 0; i < 2; ++i) {
        u32 a = pp[f][4 * k2 + i];
        u32 b2 = pp[f][4 * k2 + 2 + i];
        asm volatile("v_permlane32_swap_b32 %0, %1" : "+v"(a), "+v"(b2));
        afv[ks][i] = a;       // {lo-half pair m, per-target-hi}
        afv[ks][2 + i] = b2;  // {hi-half pair m}
      }
    }

    // PV: oacc[q][d] += P[q][key] V[key][d]
    __builtin_amdgcn_s_setprio(1);
#pragma unroll
    for (int df = 0; df < 4; ++df) {
      int d = df * 32 + kl;
#pragma unroll
      for (int ks = 0; ks < 4; ++ks) {
        int byteoff = d * 128 + ((((ks << 1) + hi) ^ (kl & 7)) << 4);
        bf16x8 vf = *reinterpret_cast<const bf16x8*>((const char*)Vts + byteoff);
        bf16x8 pa = __builtin_bit_cast(bf16x8, afv[ks]);
        oacc[df] = __builtin_amdgcn_mfma_f32_32x32x16_bf16(pa, vf, oacc[df], 0, 0, 0);
      }
    }
    __builtin_amdgcn_s_setprio(0);
  }

  // epilogue: merge half-wave sums, normalize, head mask, write bf16 [t][c]
  float lt = lsum + __shfl_xor(lsum, 32);
  float hm = mask6[h];
  float inv_l = hm / lt;           // valid for q-row = kl at this lane
#pragma unroll
  for (int r = 0; r < 16; ++r) {
    int qloc = (r & 3) + 8 * (r >> 2) + 4 * hi;
    float invr = __shfl(inv_l, qloc);
    int n = q0 + qloc;
#pragma unroll
    for (int df = 0; df < 4; ++df) {
      int d = df * 32 + kl;
      ab[((size_t)b * SEQ_ + n) * DIM_ + h * HD_ + d] = (bf16)(oacc[df][r] * invr);
    }
  }
}

extern "C" void kernel_launch(void* const* d_in, const int* in_sizes, int n_in,
                              void* d_out, int out_size, void* d_ws, size_t ws_size,
                              hipStream_t stream) {
  const float* x        = (const float*)d_in[0];
  const float* latency  = (const float*)d_in[1];
  const float* qkv_w    = (const float*)d_in[2];
  const float* qkv_b    = (const float*)d_in[3];
  const float* proj_w   = (const float*)d_in[4];
  const float* proj_b   = (const float*)d_in[5];
  const float* router_w = (const float*)d_in[6];
  const float* router_b = (const float*)d_in[7];
  const float* g1       = (const float*)d_in[8];
  const float* g2       = (const float*)d_in[9];
  float* out = (float*)d_out;

  const size_t N_X  = (size_t)TOK_ * DIM_;
  const size_t N_WQ = (size_t)OUT3_ * DIM_;
  const size_t N_WP = (size_t)DIM_ * DIM_;
  const size_t N_P  = (size_t)NB_ * H_ * SEQ_ * HD_;

  float* maskp = (float*)d_ws;
  bf16* xb  = (bf16*)((char*)d_ws + 256);
  bf16* wqb = xb + N_X;
  bf16* wpb = wqb + N_WQ;
  bf16* qbf = wpb + N_WP;
  bf16* kbf = qbf + N_P;
  bf16* vtb = kbf + N_P;
  bf16* abf = vtb + N_P;

  size_t need = 256 + 2 * (N_X + N_WQ + N_WP + 4 * N_P);
  if (ws_size < need) return;

  convert_kernel<<<(int)(N_X / 1024), 256, 0, stream>>>(x, xb, (int)N_X);
  convert_kernel<<<(int)(N_WQ / 1024), 256, 0, stream>>>(qkv_w, wqb, (int)N_WQ);
  convert_kernel<<<(int)(N_WP / 1024), 256, 0, stream>>>(proj_w, wpb, (int)N_WP);
  mask_kernel<<<1, 64, 0, stream>>>(latency, router_w, router_b, g1, g2, maskp);

  qkv_gemm<<<dim3(OUT3_ / 128, TOK_ / 128), 256, 0, stream>>>(xb, wqb, qkv_b, qbf, kbf, vtb);
  attn_kernel<<<dim3(24 * (SEQ_ / 64)), 128, 0, stream>>>(qbf, kbf, vtb, maskp, abf);
  proj_gemm<<<dim3(DIM_ / 128, TOK_ / 128), 256, 0, stream>>>(abf, wpb, proj_b, out);
}